// Round 3
// baseline (644.032 us; speedup 1.0000x reference)
//
#include <hip/hip_runtime.h>

// Problem constants
#define B_TOTAL 131072
#define HS 258    // h_lds row stride (floats)
#define TS 264    // t_lds row stride (ushort, 16B-aligned rows)
#define PS 193    // p_lds row stride (floats)

typedef short short8v __attribute__((ext_vector_type(8)));
typedef float f32x4 __attribute__((ext_vector_type(4)));

__device__ __forceinline__ unsigned short f2bf(float f) {
  union { float f; unsigned u; } v; v.f = f;
  unsigned r = v.u + 0x7FFFu + ((v.u >> 16) & 1u);
  return (unsigned short)(r >> 16);
}

// ws layout in bf16 elements
#define W_IN_OFF   0         // 256 x 32
#define W0A_OFF    8192      // 256 x 256
#define W1A_OFF    73728
#define W0B_OFF    139264
#define W1B_OFF    204800
#define WOUT_OFF   270336    // 768 x 256 (padded: row = dim*24 + j, j==23 zero)
#define WS_ELEMS   466944

__global__ void prep_weights(const float* __restrict__ w_in,
                             const float* __restrict__ w0a,
                             const float* __restrict__ w1a,
                             const float* __restrict__ w0b,
                             const float* __restrict__ w1b,
                             const float* __restrict__ w_out,
                             unsigned short* __restrict__ ws) {
  int idx = blockIdx.x * 256 + threadIdx.x;
  if (idx >= WS_ELEMS) return;
  float v;
  if (idx < W0A_OFF)       v = w_in[idx];
  else if (idx < W1A_OFF)  v = w0a[idx - W0A_OFF];
  else if (idx < W0B_OFF)  v = w1a[idx - W1A_OFF];
  else if (idx < W1B_OFF)  v = w0b[idx - W0B_OFF];
  else if (idx < WOUT_OFF) v = w1b[idx - W1B_OFF];
  else {
    int p = idx - WOUT_OFF;
    int row = p >> 8, k = p & 255;       // row < 768
    int dim = row / 24, j = row - dim * 24;
    v = (j < 23) ? w_out[(dim * 23 + j) * 256 + k] : 0.f;
  }
  ws[idx] = f2bf(v);
}

__global__ __launch_bounds__(256, 1)
void fused_main(const float* __restrict__ inp,
                const float* __restrict__ b_in,
                const float* __restrict__ b0a, const float* __restrict__ b1a,
                const float* __restrict__ b0b, const float* __restrict__ b1b,
                const float* __restrict__ b_out,
                const unsigned short* __restrict__ ws,
                float* __restrict__ outp) {
  __shared__ float h_lds[64 * HS];            // 66048 B
  __shared__ unsigned short t_lds[64 * TS];   // 33792 B
  __shared__ float p_lds[32 * PS];            // 24704 B

  const int tid  = threadIdx.x;
  const int lane = tid & 63;
  const int wave = tid >> 6;       // 0..3
  const int l15  = lane & 15;
  const int lhi  = lane >> 4;      // 0..3
  const int row0 = blockIdx.x * 64;

  const f32x4 zero4 = {0.f, 0.f, 0.f, 0.f};

  // ================= Layer in: h = ident @ w_in^T + b_in (K = 32) ===========
  {
    f32x4 acc[4][4];
#pragma unroll
    for (int mi = 0; mi < 4; mi++)
#pragma unroll
      for (int ni = 0; ni < 4; ni++) acc[mi][ni] = zero4;

    short8v a[4];
#pragma unroll
    for (int mi = 0; mi < 4; mi++) {
      int rg = row0 + mi * 16 + l15;
      const float* src = inp + (long)rg * 64;
      int kb = lhi * 8;
#pragma unroll
      for (int i = 0; i < 8; i++)
        a[mi][i] = (short)f2bf(src[2 * (kb + i) + 1]);   // odd cols = ident
    }
    short8v b[4];
#pragma unroll
    for (int ni = 0; ni < 4; ni++) {
      int col = wave * 64 + ni * 16 + l15;
      b[ni] = *(const short8v*)(ws + W_IN_OFF + col * 32 + lhi * 8);
    }
#pragma unroll
    for (int mi = 0; mi < 4; mi++)
#pragma unroll
      for (int ni = 0; ni < 4; ni++)
        acc[mi][ni] = __builtin_amdgcn_mfma_f32_16x16x32_bf16(a[mi], b[ni], acc[mi][ni], 0, 0, 0);

#pragma unroll
    for (int ni = 0; ni < 4; ni++) {
      int col = wave * 64 + ni * 16 + l15;
      float bias = b_in[col];
#pragma unroll
      for (int mi = 0; mi < 4; mi++)
#pragma unroll
        for (int r = 0; r < 4; r++) {
          int rl = mi * 16 + lhi * 4 + r;
          h_lds[rl * HS + col] = acc[mi][ni][r] + bias;
        }
    }
  }
  __syncthreads();

  // ================= 2 residual blocks ======================================
#pragma unroll
  for (int blk = 0; blk < 2; ++blk) {
    const unsigned short* wAp = ws + (blk == 0 ? W0A_OFF : W0B_OFF);
    const unsigned short* wBp = ws + (blk == 0 ? W1A_OFF : W1B_OFF);
    const float* bAp = (blk == 0) ? b0a : b0b;
    const float* bBp = (blk == 0) ? b1a : b1b;

    // ---- step A: t = relu( relu(h) @ w0^T + b0 ) -> t_lds (bf16) ----
    {
      f32x4 acc[4][4];
#pragma unroll
      for (int mi = 0; mi < 4; mi++)
#pragma unroll
        for (int ni = 0; ni < 4; ni++) acc[mi][ni] = zero4;

      for (int kk = 0; kk < 8; ++kk) {
        int kb = kk * 32 + lhi * 8;
        short8v a[4];
#pragma unroll
        for (int mi = 0; mi < 4; mi++) {
          int rl = mi * 16 + l15;
          const float* hp = &h_lds[rl * HS + kb];
#pragma unroll
          for (int i = 0; i < 8; i++)
            a[mi][i] = (short)f2bf(fmaxf(hp[i], 0.f));
        }
        short8v b[4];
#pragma unroll
        for (int ni = 0; ni < 4; ni++) {
          int col = wave * 64 + ni * 16 + l15;
          b[ni] = *(const short8v*)(wAp + col * 256 + kb);
        }
#pragma unroll
        for (int mi = 0; mi < 4; mi++)
#pragma unroll
          for (int ni = 0; ni < 4; ni++)
            acc[mi][ni] = __builtin_amdgcn_mfma_f32_16x16x32_bf16(a[mi], b[ni], acc[mi][ni], 0, 0, 0);
      }
#pragma unroll
      for (int ni = 0; ni < 4; ni++) {
        int col = wave * 64 + ni * 16 + l15;
        float bias = bAp[col];
#pragma unroll
        for (int mi = 0; mi < 4; mi++)
#pragma unroll
          for (int r = 0; r < 4; r++) {
            int rl = mi * 16 + lhi * 4 + r;
            t_lds[rl * TS + col] = f2bf(fmaxf(acc[mi][ni][r] + bias, 0.f));
          }
      }
    }
    __syncthreads();

    // ---- step B: h += t @ w1^T + b1 ----
    {
      f32x4 acc[4][4];
#pragma unroll
      for (int mi = 0; mi < 4; mi++)
#pragma unroll
        for (int ni = 0; ni < 4; ni++) acc[mi][ni] = zero4;

      for (int kk = 0; kk < 8; ++kk) {
        int kb = kk * 32 + lhi * 8;
        short8v a[4];
#pragma unroll
        for (int mi = 0; mi < 4; mi++) {
          int rl = mi * 16 + l15;
          a[mi] = *(const short8v*)&t_lds[rl * TS + kb];
        }
        short8v b[4];
#pragma unroll
        for (int ni = 0; ni < 4; ni++) {
          int col = wave * 64 + ni * 16 + l15;
          b[ni] = *(const short8v*)(wBp + col * 256 + kb);
        }
#pragma unroll
        for (int mi = 0; mi < 4; mi++)
#pragma unroll
          for (int ni = 0; ni < 4; ni++)
            acc[mi][ni] = __builtin_amdgcn_mfma_f32_16x16x32_bf16(a[mi], b[ni], acc[mi][ni], 0, 0, 0);
      }
#pragma unroll
      for (int ni = 0; ni < 4; ni++) {
        int col = wave * 64 + ni * 16 + l15;
        float bias = bBp[col];
#pragma unroll
        for (int mi = 0; mi < 4; mi++)
#pragma unroll
          for (int r = 0; r < 4; r++) {
            int rl = mi * 16 + lhi * 4 + r;
            h_lds[rl * HS + col] += acc[mi][ni][r] + bias;
          }
      }
    }
    __syncthreads();
  }

  // ================= Output layer + spline ==================================
  float lad0 = 0.f, lad1 = 0.f;
  const int dl  = tid & 7;    // dim-slot within chunk
  const int rsp = tid >> 3;   // 0..31 row within half

  for (int chunk = 0; chunk < 4; ++chunk) {
    f32x4 acc[4][3];
#pragma unroll
    for (int mi = 0; mi < 4; mi++)
#pragma unroll
      for (int ni = 0; ni < 3; ni++) acc[mi][ni] = zero4;

    for (int kk = 0; kk < 8; ++kk) {
      int kb = kk * 32 + lhi * 8;
      short8v a[4];
#pragma unroll
      for (int mi = 0; mi < 4; mi++) {
        int rl = mi * 16 + l15;
        const float* hp = &h_lds[rl * HS + kb];
#pragma unroll
        for (int i = 0; i < 8; i++)
          a[mi][i] = (short)f2bf(hp[i]);      // NO relu on final layer
      }
      short8v b[3];
#pragma unroll
      for (int ni = 0; ni < 3; ni++) {
        int col = chunk * 192 + wave * 48 + ni * 16 + l15;
        b[ni] = *(const short8v*)(ws + WOUT_OFF + col * 256 + kb);
      }
#pragma unroll
      for (int mi = 0; mi < 4; mi++)
#pragma unroll
        for (int ni = 0; ni < 3; ni++)
          acc[mi][ni] = __builtin_amdgcn_mfma_f32_16x16x32_bf16(a[mi], b[ni], acc[mi][ni], 0, 0, 0);
    }

#pragma unroll
    for (int half = 0; half < 2; ++half) {
      // stage this half's params (+ b_out) into LDS
#pragma unroll
      for (int ni = 0; ni < 3; ni++) {
        int cl = wave * 48 + ni * 16 + l15;   // 0..191
        int cg = chunk * 192 + cl;
        int dim = cg / 24;
        int j = cg - dim * 24;
        float bias = (j < 23) ? b_out[dim * 23 + j] : 0.f;
#pragma unroll
        for (int mi2 = 0; mi2 < 2; mi2++)
#pragma unroll
          for (int r = 0; r < 4; r++) {
            int rl = mi2 * 16 + lhi * 4 + r;  // 0..31
            if (j < 23)
              p_lds[rl * PS + cl] = acc[half * 2 + mi2][ni][r] + bias;
          }
      }
      __syncthreads();

      // spline: one (row, dim) per thread
      {
        const float S = 0.0625f;
        int dg = chunk * 8 + dl;
        int rg = row0 + half * 32 + rsp;
        const float* pb = &p_lds[rsp * PS + dl * 24];

        float2 xin = *(const float2*)(inp + (long)rg * 64 + 2 * dg);
        float x = xin.x, idv = xin.y;

        float pw[8], ph[8];
#pragma unroll
        for (int i = 0; i < 8; i++) { pw[i] = pb[i] * S; ph[i] = pb[8 + i] * S; }
        float mw = pw[0], mh = ph[0];
#pragma unroll
        for (int i = 1; i < 8; i++) { mw = fmaxf(mw, pw[i]); mh = fmaxf(mh, ph[i]); }
        float ew[8], eh[8], sw = 0.f, sh = 0.f;
#pragma unroll
        for (int i = 0; i < 8; i++) {
          ew[i] = expf(pw[i] - mw); sw += ew[i];
          eh[i] = expf(ph[i] - mh); sh += eh[i];
        }
        float invw = 0.992f / sw, invh = 0.992f / sh;

        float dv[9];
        dv[0] = 1.f; dv[8] = 1.f;
#pragma unroll
        for (int i = 1; i < 8; i++) {
          float u = pb[16 + i - 1];
          float sp = (u > 15.f) ? u : log1pf(expf(u));
          dv[i] = 0.001f + sp;
        }

        bool inside = (x >= -3.f) && (x <= 3.f);
        float xc = fminf(3.f, fmaxf(-3.f, x));

        float elo = -3.f, flo = -3.f, cw = 0.f, ch = 0.f;
        float in_cw = -3.f, in_w = 1.f, in_ch = -3.f, in_h = 1.f, in_d = 1.f, in_dp1 = 1.f;
#pragma unroll
        for (int i = 0; i < 8; i++) {
          float wi = 0.001f + ew[i] * invw; cw += wi;
          float hi = 0.001f + eh[i] * invh; ch += hi;
          float ehi = (i == 7) ? 3.f : 6.f * cw - 3.f;
          float fhi = (i == 7) ? 3.f : 6.f * ch - 3.f;
          bool take = (i == 0) || (xc >= elo);
          if (take) {
            in_cw = elo; in_w = ehi - elo;
            in_ch = flo; in_h = fhi - flo;
            in_d = dv[i]; in_dp1 = dv[i + 1];
          }
          elo = ehi; flo = fhi;
        }

        float th  = (xc - in_cw) / in_w;
        float omt = 1.f - th;
        float tom = th * omt;
        float delta = in_h / in_w;
        float num = in_h * (delta * th * th + in_d * tom);
        float den = delta + (in_d + in_dp1 - 2.f * delta) * tom;
        float y = in_ch + num / den;
        float dnum = delta * delta * (in_dp1 * th * th + 2.f * delta * tom + in_d * omt * omt);
        float lad = logf(dnum) - 2.f * logf(den);

        float yout = inside ? y : x;
        float ladv = inside ? lad : 0.f;

        float2 o; o.x = yout; o.y = idv;
        *(float2*)(outp + (long)rg * 64 + 2 * dg) = o;

        if (half == 0) lad0 += ladv; else lad1 += ladv;
      }
      __syncthreads();
    }
  }

  // lad reduction over the 8 dim-slots sharing a row
#pragma unroll
  for (int off = 1; off < 8; off <<= 1) {
    lad0 += __shfl_xor(lad0, off);
    lad1 += __shfl_xor(lad1, off);
  }
  if (dl == 0) {
    outp[(long)B_TOTAL * 64 + row0 + rsp]      = lad0;
    outp[(long)B_TOTAL * 64 + row0 + 32 + rsp] = lad1;
  }
}

extern "C" void kernel_launch(void* const* d_in, const int* in_sizes, int n_in,
                              void* d_out, int out_size, void* d_ws, size_t ws_size,
                              hipStream_t stream) {
  const float* inputs = (const float*)d_in[0];
  const float* w_in   = (const float*)d_in[1];
  const float* b_in   = (const float*)d_in[2];
  const float* w0a    = (const float*)d_in[3];
  const float* b0a    = (const float*)d_in[4];
  const float* w1a    = (const float*)d_in[5];
  const float* b1a    = (const float*)d_in[6];
  const float* w0b    = (const float*)d_in[7];
  const float* b0b    = (const float*)d_in[8];
  const float* w1b    = (const float*)d_in[9];
  const float* b1b    = (const float*)d_in[10];
  const float* w_out  = (const float*)d_in[11];
  const float* b_out  = (const float*)d_in[12];
  unsigned short* ws  = (unsigned short*)d_ws;
  float* outp = (float*)d_out;

  prep_weights<<<dim3((WS_ELEMS + 255) / 256), dim3(256), 0, stream>>>(
      w_in, w0a, w1a, w0b, w1b, w_out, ws);
  fused_main<<<dim3(2048), dim3(256), 0, stream>>>(
      inputs, b_in, b0a, b1a, b0b, b1b, b_out, ws, outp);
}

// Round 5
// 390.667 us; speedup vs baseline: 1.6485x; 1.6485x over previous
//
#include <hip/hip_runtime.h>
#include <hip/hip_bf16.h>

// Problem constants
#define B_TOTAL 131072
#define TS 264    // X/Y LDS row stride (ushort); 528 B rows, 16B-aligned
#define PS 193    // p_lds row stride (floats), aliased into Y

typedef short short8v __attribute__((ext_vector_type(8)));
typedef float f32x4 __attribute__((ext_vector_type(4)));

__device__ __forceinline__ unsigned short f2bf(float f) {   // RNE, used in prep only
  union { float f; unsigned u; } v; v.f = f;
  unsigned r = v.u + 0x7FFFu + ((v.u >> 16) & 1u);
  return (unsigned short)(r >> 16);
}

__device__ __forceinline__ unsigned short f2bf_hw(float f) { // hot path: HW cast
  __hip_bfloat16 h = __float2bfloat16(f);
  return *reinterpret_cast<unsigned short*>(&h);
}

__device__ __forceinline__ float frcp(float x) { return __builtin_amdgcn_rcpf(x); }

// ws layout in bf16 elements
#define W_IN_OFF   0         // 256 x 32
#define W0A_OFF    8192      // 256 x 256
#define W1A_OFF    73728
#define W0B_OFF    139264
#define W1B_OFF    204800
#define WOUT_OFF   270336    // 768 x 256 (padded: row = dim*24 + j, j==23 zero)
#define WS_ELEMS   466944

__global__ void prep_weights(const float* __restrict__ w_in,
                             const float* __restrict__ w0a,
                             const float* __restrict__ w1a,
                             const float* __restrict__ w0b,
                             const float* __restrict__ w1b,
                             const float* __restrict__ w_out,
                             unsigned short* __restrict__ ws) {
  int idx = blockIdx.x * 256 + threadIdx.x;
  if (idx >= WS_ELEMS) return;
  float v;
  if (idx < W0A_OFF)       v = w_in[idx];
  else if (idx < W1A_OFF)  v = w0a[idx - W0A_OFF];
  else if (idx < W0B_OFF)  v = w1a[idx - W1A_OFF];
  else if (idx < W1B_OFF)  v = w0b[idx - W0B_OFF];
  else if (idx < WOUT_OFF) v = w1b[idx - W1B_OFF];
  else {
    int p = idx - WOUT_OFF;
    int row = p >> 8, k = p & 255;       // row < 768
    int dim = row / 24, j = row - dim * 24;
    v = (j < 23) ? w_out[(dim * 23 + j) * 256 + k] : 0.f;
  }
  ws[idx] = f2bf(v);
}

// 64 rows/WG, 4 waves; h (fp32) lives in registers (hreg = wave's 64-col slice);
// bf16 activations exchanged via X/Y LDS ping-pong; p_lds aliases Y.
__global__ __launch_bounds__(256, 2)
void fused_main(const float* __restrict__ inp,
                const float* __restrict__ b_in,
                const float* __restrict__ b0a, const float* __restrict__ b1a,
                const float* __restrict__ b0b, const float* __restrict__ b1b,
                const float* __restrict__ b_out,
                const unsigned short* __restrict__ ws,
                float* __restrict__ outp) {
  __shared__ unsigned short Xs[64 * TS];   // 33792 B
  __shared__ unsigned short Ys[64 * TS];   // 33792 B

  const int tid  = threadIdx.x;
  const int lane = tid & 63;
  const int wave = tid >> 6;       // 0..3
  const int l15  = lane & 15;
  const int lhi  = lane >> 4;      // 0..3
  const int row0 = blockIdx.x * 64;

  const f32x4 zero4 = {0.f, 0.f, 0.f, 0.f};

  f32x4 hreg[4][4];                // fp32 h: rows mi*16+lhi*4+r, col wave*64+ni*16+l15

  // ================= Layer in: h = ident @ w_in^T + b_in (K = 32) ===========
  {
#pragma unroll
    for (int mi = 0; mi < 4; mi++)
#pragma unroll
      for (int ni = 0; ni < 4; ni++) hreg[mi][ni] = zero4;

    short8v a[4];
#pragma unroll
    for (int mi = 0; mi < 4; mi++) {
      int rg = row0 + mi * 16 + l15;
      const float2* s2 = (const float2*)(inp + (long)rg * 64) + lhi * 8;
#pragma unroll
      for (int i = 0; i < 8; i++)
        a[mi][i] = (short)f2bf_hw(s2[i].y);   // odd cols = ident
    }
    short8v b[4];
#pragma unroll
    for (int ni = 0; ni < 4; ni++) {
      int col = wave * 64 + ni * 16 + l15;
      b[ni] = *(const short8v*)(ws + W_IN_OFF + col * 32 + lhi * 8);
    }
#pragma unroll
    for (int mi = 0; mi < 4; mi++)
#pragma unroll
      for (int ni = 0; ni < 4; ni++)
        hreg[mi][ni] = __builtin_amdgcn_mfma_f32_16x16x32_bf16(a[mi], b[ni], hreg[mi][ni], 0, 0, 0);

    // bias + write relu(h) bf16 -> X
#pragma unroll
    for (int ni = 0; ni < 4; ni++) {
      int col = wave * 64 + ni * 16 + l15;
      float bias = b_in[col];
#pragma unroll
      for (int mi = 0; mi < 4; mi++)
#pragma unroll
        for (int r = 0; r < 4; r++) {
          hreg[mi][ni][r] += bias;
          int rl = mi * 16 + lhi * 4 + r;
          Xs[rl * TS + col] = f2bf_hw(fmaxf(hreg[mi][ni][r], 0.f));
        }
    }
  }
  __syncthreads();

  // ================= 2 residual blocks ======================================
#pragma unroll
  for (int blk = 0; blk < 2; ++blk) {
    const unsigned short* wAp = ws + (blk == 0 ? W0A_OFF : W0B_OFF);
    const unsigned short* wBp = ws + (blk == 0 ? W1A_OFF : W1B_OFF);
    const float* bAp = (blk == 0) ? b0a : b0b;
    const float* bBp = (blk == 0) ? b1a : b1b;

    // ---- step A: t = relu( X @ w0^T + b0 ) -> Y (bf16) ----
    {
      f32x4 acc[4][4];
#pragma unroll
      for (int mi = 0; mi < 4; mi++)
#pragma unroll
        for (int ni = 0; ni < 4; ni++) acc[mi][ni] = zero4;

      for (int kk = 0; kk < 8; ++kk) {
        int kb = kk * 32 + lhi * 8;
        short8v a[4];
#pragma unroll
        for (int mi = 0; mi < 4; mi++)
          a[mi] = *(const short8v*)&Xs[(mi * 16 + l15) * TS + kb];
        short8v b[4];
#pragma unroll
        for (int ni = 0; ni < 4; ni++) {
          int col = wave * 64 + ni * 16 + l15;
          b[ni] = *(const short8v*)(wAp + col * 256 + kb);
        }
#pragma unroll
        for (int mi = 0; mi < 4; mi++)
#pragma unroll
          for (int ni = 0; ni < 4; ni++)
            acc[mi][ni] = __builtin_amdgcn_mfma_f32_16x16x32_bf16(a[mi], b[ni], acc[mi][ni], 0, 0, 0);
      }
#pragma unroll
      for (int ni = 0; ni < 4; ni++) {
        int col = wave * 64 + ni * 16 + l15;
        float bias = bAp[col];
#pragma unroll
        for (int mi = 0; mi < 4; mi++)
#pragma unroll
          for (int r = 0; r < 4; r++) {
            int rl = mi * 16 + lhi * 4 + r;
            Ys[rl * TS + col] = f2bf_hw(fmaxf(acc[mi][ni][r] + bias, 0.f));
          }
      }
    }
    __syncthreads();

    // ---- step B: h += Y @ w1^T + b1; write (relu(h) | h) bf16 -> X ----
    {
      f32x4 acc[4][4];
#pragma unroll
      for (int mi = 0; mi < 4; mi++)
#pragma unroll
        for (int ni = 0; ni < 4; ni++) acc[mi][ni] = zero4;

      for (int kk = 0; kk < 8; ++kk) {
        int kb = kk * 32 + lhi * 8;
        short8v a[4];
#pragma unroll
        for (int mi = 0; mi < 4; mi++)
          a[mi] = *(const short8v*)&Ys[(mi * 16 + l15) * TS + kb];
        short8v b[4];
#pragma unroll
        for (int ni = 0; ni < 4; ni++) {
          int col = wave * 64 + ni * 16 + l15;
          b[ni] = *(const short8v*)(wBp + col * 256 + kb);
        }
#pragma unroll
        for (int mi = 0; mi < 4; mi++)
#pragma unroll
          for (int ni = 0; ni < 4; ni++)
            acc[mi][ni] = __builtin_amdgcn_mfma_f32_16x16x32_bf16(a[mi], b[ni], acc[mi][ni], 0, 0, 0);
      }
#pragma unroll
      for (int ni = 0; ni < 4; ni++) {
        int col = wave * 64 + ni * 16 + l15;
        float bias = bBp[col];
#pragma unroll
        for (int mi = 0; mi < 4; mi++)
#pragma unroll
          for (int r = 0; r < 4; r++) {
            hreg[mi][ni][r] += acc[mi][ni][r] + bias;
            float hv = hreg[mi][ni][r];
            int rl = mi * 16 + lhi * 4 + r;
            Xs[rl * TS + col] = f2bf_hw(blk == 0 ? fmaxf(hv, 0.f) : hv);
          }
      }
    }
    __syncthreads();
  }

  // ================= Output layer + spline ==================================
  float* p_lds = reinterpret_cast<float*>(Ys);   // 32*PS*4 = 24704 <= 33792 B

  float lad0 = 0.f, lad1 = 0.f;
  const int dl  = tid & 7;    // dim-slot within chunk
  const int rsp = tid >> 3;   // 0..31 row within half

  for (int chunk = 0; chunk < 4; ++chunk) {
    f32x4 acc[4][3];
#pragma unroll
    for (int mi = 0; mi < 4; mi++)
#pragma unroll
      for (int ni = 0; ni < 3; ni++) acc[mi][ni] = zero4;

    for (int kk = 0; kk < 8; ++kk) {
      int kb = kk * 32 + lhi * 8;
      short8v a[4];
#pragma unroll
      for (int mi = 0; mi < 4; mi++)
        a[mi] = *(const short8v*)&Xs[(mi * 16 + l15) * TS + kb];
      short8v b[3];
#pragma unroll
      for (int ni = 0; ni < 3; ni++) {
        int col = chunk * 192 + wave * 48 + ni * 16 + l15;
        b[ni] = *(const short8v*)(ws + WOUT_OFF + col * 256 + kb);
      }
#pragma unroll
      for (int mi = 0; mi < 4; mi++)
#pragma unroll
        for (int ni = 0; ni < 3; ni++)
          acc[mi][ni] = __builtin_amdgcn_mfma_f32_16x16x32_bf16(a[mi], b[ni], acc[mi][ni], 0, 0, 0);
    }

#pragma unroll
    for (int half = 0; half < 2; ++half) {
      // stage this half's params (+ b_out) into p_lds (aliases Y)
#pragma unroll
      for (int ni = 0; ni < 3; ni++) {
        int cl = wave * 48 + ni * 16 + l15;   // 0..191
        int cg = chunk * 192 + cl;
        int dim = cg / 24;
        int j = cg - dim * 24;
        float bias = (j < 23) ? b_out[dim * 23 + j] : 0.f;
#pragma unroll
        for (int mi2 = 0; mi2 < 2; mi2++)
#pragma unroll
          for (int r = 0; r < 4; r++) {
            int rl = mi2 * 16 + lhi * 4 + r;  // 0..31
            if (j < 23)
              p_lds[rl * PS + cl] = acc[half * 2 + mi2][ni][r] + bias;
          }
      }
      __syncthreads();

      // spline: one (row, dim) per thread
      {
        const float S = 0.0625f;
        int dg = chunk * 8 + dl;
        int rg = row0 + half * 32 + rsp;
        const float* pb = &p_lds[rsp * PS + dl * 24];

        float2 xin = *(const float2*)(inp + (long)rg * 64 + 2 * dg);
        float x = xin.x, idv = xin.y;

        float pw[8], ph[8];
#pragma unroll
        for (int i = 0; i < 8; i++) { pw[i] = pb[i] * S; ph[i] = pb[8 + i] * S; }
        float mw = pw[0], mh = ph[0];
#pragma unroll
        for (int i = 1; i < 8; i++) { mw = fmaxf(mw, pw[i]); mh = fmaxf(mh, ph[i]); }
        float ew[8], eh[8], sw = 0.f, sh = 0.f;
#pragma unroll
        for (int i = 0; i < 8; i++) {
          ew[i] = __expf(pw[i] - mw); sw += ew[i];
          eh[i] = __expf(ph[i] - mh); sh += eh[i];
        }
        float invw = 0.992f * frcp(sw), invh = 0.992f * frcp(sh);

        float dv[9];
        dv[0] = 1.f; dv[8] = 1.f;
#pragma unroll
        for (int i = 1; i < 8; i++) {
          float u = pb[16 + i - 1];
          float sp = (u > 15.f) ? u : __logf(1.f + __expf(u));
          dv[i] = 0.001f + sp;
        }

        bool inside = (x >= -3.f) && (x <= 3.f);
        float xc = fminf(3.f, fmaxf(-3.f, x));

        float elo = -3.f, flo = -3.f, cw = 0.f, ch = 0.f;
        float in_cw = -3.f, in_w = 1.f, in_ch = -3.f, in_h = 1.f, in_d = 1.f, in_dp1 = 1.f;
#pragma unroll
        for (int i = 0; i < 8; i++) {
          float wi = 0.001f + ew[i] * invw; cw += wi;
          float hi = 0.001f + eh[i] * invh; ch += hi;
          float ehi = (i == 7) ? 3.f : 6.f * cw - 3.f;
          float fhi = (i == 7) ? 3.f : 6.f * ch - 3.f;
          bool take = (i == 0) || (xc >= elo);
          if (take) {
            in_cw = elo; in_w = ehi - elo;
            in_ch = flo; in_h = fhi - flo;
            in_d = dv[i]; in_dp1 = dv[i + 1];
          }
          elo = ehi; flo = fhi;
        }

        float rw   = frcp(in_w);
        float th   = (xc - in_cw) * rw;
        float omt  = 1.f - th;
        float tom  = th * omt;
        float delta = in_h * rw;
        float num  = in_h * (delta * th * th + in_d * tom);
        float den  = delta + (in_d + in_dp1 - 2.f * delta) * tom;
        float y    = in_ch + num * frcp(den);
        float dnum = delta * delta * (in_dp1 * th * th + 2.f * delta * tom + in_d * omt * omt);
        float lad  = __logf(dnum) - 2.f * __logf(den);

        float yout = inside ? y : x;
        float ladv = inside ? lad : 0.f;

        float2 o; o.x = yout; o.y = idv;
        *(float2*)(outp + (long)rg * 64 + 2 * dg) = o;

        if (half == 0) lad0 += ladv; else lad1 += ladv;
      }
      __syncthreads();
    }
  }

  // lad reduction over the 8 dim-slots sharing a row
#pragma unroll
  for (int off = 1; off < 8; off <<= 1) {
    lad0 += __shfl_xor(lad0, off);
    lad1 += __shfl_xor(lad1, off);
  }
  if (dl == 0) {
    outp[(long)B_TOTAL * 64 + row0 + rsp]      = lad0;
    outp[(long)B_TOTAL * 64 + row0 + 32 + rsp] = lad1;
  }
}

extern "C" void kernel_launch(void* const* d_in, const int* in_sizes, int n_in,
                              void* d_out, int out_size, void* d_ws, size_t ws_size,
                              hipStream_t stream) {
  const float* inputs = (const float*)d_in[0];
  const float* w_in   = (const float*)d_in[1];
  const float* b_in   = (const float*)d_in[2];
  const float* w0a    = (const float*)d_in[3];
  const float* b0a    = (const float*)d_in[4];
  const float* w1a    = (const float*)d_in[5];
  const float* b1a    = (const float*)d_in[6];
  const float* w0b    = (const float*)d_in[7];
  const float* b0b    = (const float*)d_in[8];
  const float* w1b    = (const float*)d_in[9];
  const float* b1b    = (const float*)d_in[10];
  const float* w_out  = (const float*)d_in[11];
  const float* b_out  = (const float*)d_in[12];
  unsigned short* ws  = (unsigned short*)d_ws;
  float* outp = (float*)d_out;

  prep_weights<<<dim3((WS_ELEMS + 255) / 256), dim3(256), 0, stream>>>(
      w_in, w0a, w1a, w0b, w1b, w_out, ws);
  fused_main<<<dim3(2048), dim3(256), 0, stream>>>(
      inputs, b_in, b0a, b1a, b0b, b1b, b_out, ws, outp);
}